// Round 1
// 81.436 us; speedup vs baseline: 1.0263x; 1.0263x over previous
//
#include <hip/hip_runtime.h>

// JPEG-compression-as-augmentation, collapsed to luma-only per-channel codec.
// Chroma planes of a gray (v,v,v) image are exactly 128 and the chroma codec
// is an exact fixed point, so only the Y path survives. Per (B,C) channel:
//   min/max normalize -> *255 -> edge-pad 14x14 -> 16x16 -> 4 blocks of 8x8
//   R = C^T * diffround( C*(X-128)*C^T / (Y_T*f) ) * (Y_T*f) * C + 128
//   out = clip(R,0,255)/255 * rng + min        (f = 0.02 at quality 99)
//
// Round-5 changes vs round-4 (passed, absmax 1.56e-2, dur 83.5):
//  * pass 4 now fuses crop(1:-1) + (+128) + clip + un-normalize and scatters
//    the final pixels into a NATURAL 14x14 plane in the dead s_A region
//    (stride-14 column writes: per-k banks distinct, row-groups 16 banks
//    apart, cross-channel offset 196 -> worst 2-way = free). Output stage
//    collapses from ~160 instr/lane of gather/address math to a pure
//    2x(ds_read_b128 + global_store_dwordx4) copy.
//  * per-lane mn/scale used directly in pass 4 -> 4 broadcast shuffles gone.
//  * quant divisors come from a transposed, compile-time-prescaled table
//    QVT[i][k] = Y_T[k][i]*0.02f (bit-identical to the runtime fp32 mul),
//    loaded as 2 float4 per lane while the staging DMA is in flight ->
//    removes 8 scalar global loads + 8 muls from pass 2's hot loop.
//  * __launch_bounds__(256,8): post-cleanup live state ~45 regs; target 64
//    VGPR so the 8 LDS-permitted blocks/CU give full 32 waves/CU.
// Retained: barrier-free per-wave ownership (all sync is intra-wave
// s_waitcnt), global_load_lds width-16 staging, raw aliased into bufA,
// stride-9/72 bank-bijective block layout, EXACT fp32 quant divide
// (round-boundary sensitive - do not trade ulps), float4 global I/O.

namespace {

constexpr int CH_PER_WG = 8;   // 4 waves * 2 channels
constexpr int HW        = 196; // 14*14
constexpr int CS        = 288; // per-channel block storage: 4 blocks * (8 rows * stride 9)
constexpr int WREG      = 2 * CS; // per-wave region (2 channels) in each buffer

// Orthonormal 8-point DCT-II matrix: CM[u][x] = 0.5*alpha_u*cos((2x+1)u*pi/16).
constexpr float CM[8][8] = {
  { 0.35355339059327376f,  0.35355339059327376f,  0.35355339059327376f,  0.35355339059327376f,
    0.35355339059327376f,  0.35355339059327376f,  0.35355339059327376f,  0.35355339059327376f},
  { 0.49039264020161522f,  0.41573480615127262f,  0.27778511650980114f,  0.09754516100806417f,
   -0.09754516100806417f, -0.27778511650980114f, -0.41573480615127262f, -0.49039264020161522f},
  { 0.46193976625564337f,  0.19134171618254492f, -0.19134171618254492f, -0.46193976625564337f,
   -0.46193976625564337f, -0.19134171618254492f,  0.19134171618254492f,  0.46193976625564337f},
  { 0.41573480615127262f, -0.09754516100806417f, -0.49039264020161522f, -0.27778511650980114f,
    0.27778511650980114f,  0.49039264020161522f,  0.09754516100806417f, -0.41573480615127262f},
  { 0.35355339059327376f, -0.35355339059327376f, -0.35355339059327376f,  0.35355339059327376f,
    0.35355339059327376f, -0.35355339059327376f, -0.35355339059327376f,  0.35355339059327376f},
  { 0.27778511650980114f, -0.49039264020161522f,  0.09754516100806417f,  0.41573480615127262f,
   -0.41573480615127262f, -0.09754516100806417f,  0.49039264020161522f, -0.27778511650980114f},
  { 0.19134171618254492f, -0.46193976625564337f,  0.46193976625564337f, -0.19134171618254492f,
   -0.19134171618254492f,  0.46193976625564337f, -0.46193976625564337f,  0.19134171618254492f},
  { 0.09754516100806417f, -0.27778511650980114f,  0.41573480615127262f, -0.49039264020161522f,
    0.49039264020161522f, -0.41573480615127262f,  0.27778511650980114f, -0.09754516100806417f},
};

} // namespace

// Transposed, pre-scaled luma quant table: QVT[i][k] = Y_T[k][i] * 0.02f.
// int*0.02f is constant-folded in IEEE fp32 RN -> bit-identical to the
// runtime v_mul the previous kernel executed. Row i is 16B-aligned so one
// lane reads its whole column as two float4.
#define SF 0.02f
__device__ __align__(16) const float QVT[8][8] = {
  {16*SF, 12*SF, 14*SF, 14*SF, 18*SF,  24*SF,  49*SF,  72*SF},
  {11*SF, 12*SF, 13*SF, 17*SF, 22*SF,  35*SF,  64*SF,  92*SF},
  {10*SF, 14*SF, 16*SF, 22*SF, 37*SF,  55*SF,  78*SF,  95*SF},
  {16*SF, 19*SF, 24*SF, 29*SF, 56*SF,  64*SF,  87*SF,  98*SF},
  {24*SF, 26*SF, 40*SF, 51*SF, 68*SF,  81*SF, 103*SF, 112*SF},
  {40*SF, 58*SF, 57*SF, 87*SF, 109*SF, 104*SF, 121*SF, 100*SF},
  {51*SF, 60*SF, 69*SF, 80*SF, 103*SF, 113*SF, 120*SF, 103*SF},
  {61*SF, 55*SF, 56*SF, 62*SF, 77*SF,  92*SF, 101*SF,  99*SF},
};
#undef SF

// Intra-wave fences: one wave's DS (resp. VMEM->LDS) ops complete in order
// w.r.t. its own later ops after the counter drains; with all producers and
// consumers in the same wave, no s_barrier is needed anywhere.
#define WAVE_LDS_SYNC() asm volatile("s_waitcnt lgkmcnt(0)" ::: "memory")
#define WAVE_VM_SYNC()  asm volatile("s_waitcnt vmcnt(0)" ::: "memory")

typedef __attribute__((address_space(1))) const void gvoid_t;
typedef __attribute__((address_space(3))) void       lvoid_t;

__global__ __launch_bounds__(256, 8)
void jpeg_codec_kernel(const float* __restrict__ x, float* __restrict__ out) {
  __shared__ __align__(16) float s_A[CH_PER_WG * CS];   // 9216 B (hosts raw input, then Qs, then final plane)
  __shared__ __align__(16) float s_B[CH_PER_WG * CS];   // 9216 B

  const int tid = threadIdx.x;
  const int w   = tid >> 6;       // wave 0..3
  const int wl  = tid & 63;       // lane in wave
  const int chl = (tid >> 5) & 1; // channel-in-wave 0/1
  const int l   = tid & 31;       // lane-in-channel

  // wave w owns global float4 range [g4, g4+98) = 2 channels of 49 f4 each
  const long long g4 = (long long)blockIdx.x * (CH_PER_WG * HW / 4) + w * (2 * HW / 4);

  // ---- 1. per-wave async staging: raw -> bufA[w*WREG .. +392) ----
  // global_load_lds writes lane i's 16B to (uniform lds base) + i*16, which is
  // exactly the contiguous layout we want. raw floats [0,392) of the wave
  // region; ch0 raw = [0,196), ch1 raw = [196,392).
  {
    const float4* x4 = (const float4*)x + g4;
    float* raw = s_A + w * WREG;
    __builtin_amdgcn_global_load_lds((gvoid_t*)(x4 + wl), (lvoid_t*)raw, 16, 0, 0);
    if (wl < 2 * HW / 4 - 64)  // lanes 0..33 stage f4 64..97
      __builtin_amdgcn_global_load_lds((gvoid_t*)(x4 + 64 + wl),
                                       (lvoid_t*)(raw + 256), 16, 0, 0);
  }

  const int b = l >> 3;                          // block 0..3
  const int i = l & 7;                           // row/col 0..7

  // per-lane quant column, loaded while the staging DMA is in flight
  // (L2-resident broadcast; drained by the same vmcnt fence).
  float qv8[8];
  {
    const float4* qt = (const float4*)QVT[i];
    float4 qa = qt[0], qb = qt[1];
    qv8[0] = qa.x; qv8[1] = qa.y; qv8[2] = qa.z; qv8[3] = qa.w;
    qv8[4] = qb.x; qv8[5] = qb.y; qv8[6] = qb.z; qv8[7] = qb.w;
  }

  WAVE_VM_SYNC();

  const float* raw_ch = s_A + w * WREG + chl * HW;  // this lane's channel raw

  // ---- 2. per-channel min/max: float4 reads + shuffle butterfly ----
  float mn, inv, scale;          // all uniform within the 32-lane channel group
  {
    float vmin = 1e30f, vmax = -1e30f;
    const float4* c4 = (const float4*)raw_ch;       // offsets %16 == 0
    {
      float4 v = c4[l];                             // f4 0..31
      vmin = fminf(fminf(vmin, v.x), fminf(v.y, fminf(v.z, v.w)));
      vmax = fmaxf(fmaxf(vmax, v.x), fmaxf(v.y, fmaxf(v.z, v.w)));
    }
    if (l < 17) {                                   // f4 32..48
      float4 v = c4[l + 32];
      vmin = fminf(fminf(vmin, v.x), fminf(v.y, fminf(v.z, v.w)));
      vmax = fmaxf(fmaxf(vmax, v.x), fmaxf(v.y, fmaxf(v.z, v.w)));
    }
    #pragma unroll
    for (int off = 16; off; off >>= 1) {            // xor<=16 stays in 32-group
      vmin = fminf(vmin, __shfl_xor(vmin, off, 64));
      vmax = fmaxf(vmax, __shfl_xor(vmax, off, 64));
    }
    mn = vmin;
    float rng = vmax - vmin + 1e-5f;
    inv   = 255.0f / rng;                           // the only normalize divide
    scale = rng * (1.0f / 255.0f);
  }

  // ---- 3. four separable passes over stride-9 blocks (bank-bijective) ----
  const int cbase = w * WREG + chl * CS;         // channel block-storage base
  const int rbase = cbase + b * 72 + i * 9;      // row i of block b (contig 8)
  const int wbase = cbase + b * 72 + i;          // column i (element k at +9k)

  float m[8];

  // pass 1: read padded+normalized X rows straight from raw; bufB = C*X^T
  {
    const int pr = ((b >> 1) << 3) + i;          // padded row 0..15
    int sr = pr - 1; sr = sr < 0 ? 0 : (sr > 13 ? 13 : sr);
    const float* rp = raw_ch + sr * 14;
    #pragma unroll
    for (int j = 0; j < 8; ++j) {
      int pc = ((b & 1) << 3) + j - 1; pc = pc < 0 ? 0 : (pc > 13 ? 13 : pc);
      m[j] = fmaf(rp[pc] - mn, inv, -128.0f);
    }
    #pragma unroll
    for (int k = 0; k < 8; ++k) {
      float s = 0.0f;
      #pragma unroll
      for (int j = 0; j < 8; ++j) s = fmaf(m[j], CM[k][j], s);
      s_B[wbase + 9 * k] = s;
    }
  }
  WAVE_LDS_SYNC();   // also orders: raw fully read before pass 2 clobbers it

  // pass 2: D = C*X*C^T (lane holds column i), fused quantization.
  // s/qv stays an EXACT division: it feeds rintf; round-boundary flips cost
  // up to ~0.08 absmax each — don't trade ulps here. Writes bufA (raw dead).
  #pragma unroll
  for (int j = 0; j < 8; ++j) m[j] = s_B[rbase + j];
  #pragma unroll
  for (int k = 0; k < 8; ++k) {
    float s = 0.0f;
    #pragma unroll
    for (int j = 0; j < 8; ++j) s = fmaf(m[j], CM[k][j], s);
    float qv = qv8[k];                           // tab * factor, fp32 as reference
    float xq = s / qv;
    float r  = rintf(xq);                        // round half to even == jnp.round
    float e  = xq - r;
    s_A[wbase + 9 * k] = (r + e * e * e) * qv;   // Qs in natural layout
  }
  WAVE_LDS_SYNC();

  // pass 3: bufB = (Qs*C)^T
  #pragma unroll
  for (int j = 0; j < 8; ++j) m[j] = s_A[rbase + j];
  #pragma unroll
  for (int k = 0; k < 8; ++k) {
    float s = 0.0f;
    #pragma unroll
    for (int j = 0; j < 8; ++j) s = fmaf(m[j], CM[j][k], s);
    s_B[wbase + 9 * k] = s;
  }
  WAVE_LDS_SYNC();

  // pass 4: lane holds column i of R = C^T*Qs*C. Fuse crop(1:-1) + (+128) +
  // clip + un-normalize and scatter the final pixels into a natural 14x14
  // plane at s_A[w*WREG + chl*HW .. +196) (raw/Qs regions are dead; pass-3's
  // s_A reads are already drained by the fence above). Per-k write banks are
  // distinct (14k mod 32), the two row-groups sit 16 banks apart, and the
  // cross-channel offset of 196 floats gives at worst 2 lanes/bank = free.
  {
    #pragma unroll
    for (int j = 0; j < 8; ++j) m[j] = s_B[rbase + j];
    const int pc    = ((b & 1) << 3) + i;        // padded col 0..15
    const int prb   = (b >> 1) << 3;             // padded row base 0 or 8
    const bool pcv  = (pc >= 1) && (pc <= 14);
    const int obase = prb * 14 + pc - 15;        // (pr-1)*14 + (pc-1) at k=0
    float* crop = s_A + w * WREG + chl * HW;
    #pragma unroll
    for (int k = 0; k < 8; ++k) {
      float s = 0.0f;
      #pragma unroll
      for (int j = 0; j < 8; ++j) s = fmaf(m[j], CM[j][k], s);
      const int pr = prb + k;
      if (pcv && pr >= 1 && pr <= 14) {
        float v = fminf(fmaxf(s + 128.0f, 0.0f), 255.0f);
        crop[obase + 14 * k] = fmaf(v, scale, mn);
      }
    }
  }
  WAVE_LDS_SYNC();   // wave-local: copy reads only this wave's plane

  // ---- 4. pure vectorized copy: LDS plane -> global (coalesced f4) ----
  {
    const float4* src = (const float4*)(s_A + w * WREG);
    float4* o4 = (float4*)out + g4;
    o4[wl] = src[wl];                            // f4 0..63
    if (wl < 2 * HW / 4 - 64)                    // lanes 0..33: f4 64..97
      o4[64 + wl] = src[64 + wl];
  }
}

extern "C" void kernel_launch(void* const* d_in, const int* in_sizes, int n_in,
                              void* d_out, int out_size, void* d_ws, size_t ws_size,
                              hipStream_t stream) {
  const float* x = (const float*)d_in[0];
  float* out     = (float*)d_out;
  const int ntot = in_sizes[0];                       // 32*1024*14*14
  const int nch  = ntot / HW;                         // 32768 channels
  const int grid = (nch + CH_PER_WG - 1) / CH_PER_WG; // 4096 workgroups
  hipLaunchKernelGGL(jpeg_codec_kernel, dim3(grid), dim3(256), 0, stream,
                     x, out);
}